// Round 1
// baseline (503.511 us; speedup 1.0000x reference)
//
#include <hip/hip_runtime.h>

// Problem constants
#define NITEMS 50000
#define EMBD   16
#define NSLATE 10
#define HIDD   512
#define LATD   64
#define RESPD  1024
#define BATCH  256

// d_out layout (float): z_mean[256*64] | z_log_var[256*64] | recon_slate[256*10] | recon_resp[256*10]
#define OUT_ZM 0
#define OUT_ZLV 16384
#define OUT_RS 32768
#define OUT_RR 35328

// ws layout (floats): usum[4096] cnt[256] x[307200] h[131072] dz[282624] dh[131072] rx[40960]
#define WS_USUM 0
#define WS_CNT  4096
#define WS_X    4352
#define WS_H    311552
#define WS_DZ   442624
#define WS_DH   725248
#define WS_RX   856320

__global__ __launch_bounds__(256) void zero_kernel(float* __restrict__ p, int n) {
  int i = blockIdx.x * 256 + threadIdx.x;
  if (i < n) p[i] = 0.0f;
}

// user_sum[b][e] += sum_n u[b][n]*emb[n][e]; cnt[b] += sum_n u[b][n]
__global__ __launch_bounds__(256) void pool_kernel(const int* __restrict__ u,
    const float* __restrict__ emb, float* __restrict__ usum, float* __restrict__ cnt) {
  int b = blockIdx.x;
  int n0 = blockIdx.y * 6250;
  int n1 = n0 + 6250; if (n1 > NITEMS) n1 = NITEMS;
  float acc[16];
  #pragma unroll
  for (int i = 0; i < 16; ++i) acc[i] = 0.0f;
  float c = 0.0f;
  const int* ub = u + b * NITEMS;
  for (int n = n0 + (int)threadIdx.x; n < n1; n += 256) {
    int uv = ub[n];
    if (uv) {
      const float4* e4 = (const float4*)(emb + n * 16);
      float4 a = e4[0], bb = e4[1], cc = e4[2], dd = e4[3];
      acc[0] += a.x;  acc[1] += a.y;  acc[2] += a.z;  acc[3] += a.w;
      acc[4] += bb.x; acc[5] += bb.y; acc[6] += bb.z; acc[7] += bb.w;
      acc[8] += cc.x; acc[9] += cc.y; acc[10] += cc.z; acc[11] += cc.w;
      acc[12] += dd.x; acc[13] += dd.y; acc[14] += dd.z; acc[15] += dd.w;
      c += 1.0f;
    }
  }
  #pragma unroll
  for (int off = 32; off > 0; off >>= 1) {
    #pragma unroll
    for (int i = 0; i < 16; ++i) acc[i] += __shfl_down(acc[i], off);
    c += __shfl_down(c, off);
  }
  if ((threadIdx.x & 63) == 0) {
    #pragma unroll
    for (int i = 0; i < 16; ++i) atomicAdd(&usum[b * 16 + i], acc[i]);
    atomicAdd(&cnt[b], c);
  }
}

// user = usum/cnt; x = [slate_vec(160) | user(16) | resp(1024)]; dz[64:1104] = [user | resp]
__global__ __launch_bounds__(256) void build_x_kernel(const int* __restrict__ slate,
    const float* __restrict__ resp, const float* __restrict__ emb,
    const float* __restrict__ usum, const float* __restrict__ cnt,
    float* __restrict__ x, float* __restrict__ dz) {
  int b = blockIdx.x, t = threadIdx.x;
  float inv = 1.0f / cnt[b];
  if (t < 16) {
    float uv = usum[b * 16 + t] * inv;
    x[b * 1200 + 160 + t] = uv;
    dz[b * 1104 + 64 + t] = uv;
  }
  if (t >= 32 && t < 192) {
    int i = t - 32;
    int k = i >> 4, e = i & 15;
    int it = slate[b * 10 + k];
    x[b * 1200 + i] = emb[it * 16 + e];
  }
  for (int i = t; i < 1024; i += 256) {
    float r = resp[b * 1024 + i];
    x[b * 1200 + 176 + i] = r;
    dz[b * 1104 + 80 + i] = r;
  }
}

// C[M,N] = act(A[M,K] @ B[N,K]^T + bias[N]); 32x32 tile, 2x2 microtile, K%16==0
template <bool RELU>
__global__ __launch_bounds__(256) void gemm_bias(const float* __restrict__ A,
    const float* __restrict__ B, const float* __restrict__ bias, float* __restrict__ C,
    int M, int N, int K) {
  __shared__ float As[32][33];
  __shared__ float Bs[32][33];
  int tid = threadIdx.x;
  int tx = tid & 15, ty = tid >> 4;
  int m0 = blockIdx.y * 32, n0 = blockIdx.x * 32;
  int lr = tid >> 3;          // 0..31
  int lc = (tid & 7) * 4;     // 0,4,..,28
  float acc00 = 0.f, acc01 = 0.f, acc10 = 0.f, acc11 = 0.f;
  for (int k0 = 0; k0 < K; k0 += 32) {
    float4 av = make_float4(0.f, 0.f, 0.f, 0.f);
    float4 bv = make_float4(0.f, 0.f, 0.f, 0.f);
    if (k0 + lc < K) {
      av = *(const float4*)(A + (size_t)(m0 + lr) * K + k0 + lc);
      bv = *(const float4*)(B + (size_t)(n0 + lr) * K + k0 + lc);
    }
    As[lr][lc] = av.x; As[lr][lc + 1] = av.y; As[lr][lc + 2] = av.z; As[lr][lc + 3] = av.w;
    Bs[lr][lc] = bv.x; Bs[lr][lc + 1] = bv.y; Bs[lr][lc + 2] = bv.z; Bs[lr][lc + 3] = bv.w;
    __syncthreads();
    #pragma unroll
    for (int kk = 0; kk < 32; ++kk) {
      float a0 = As[2 * ty][kk], a1 = As[2 * ty + 1][kk];
      float b0 = Bs[2 * tx][kk], b1 = Bs[2 * tx + 1][kk];
      acc00 = fmaf(a0, b0, acc00); acc01 = fmaf(a0, b1, acc01);
      acc10 = fmaf(a1, b0, acc10); acc11 = fmaf(a1, b1, acc11);
    }
    __syncthreads();
  }
  int m = m0 + 2 * ty, n = n0 + 2 * tx;
  float bb0 = bias[n], bb1 = bias[n + 1];
  float v00 = acc00 + bb0, v01 = acc01 + bb1, v10 = acc10 + bb0, v11 = acc11 + bb1;
  if (RELU) {
    v00 = fmaxf(v00, 0.f); v01 = fmaxf(v01, 0.f);
    v10 = fmaxf(v10, 0.f); v11 = fmaxf(v11, 0.f);
  }
  C[(size_t)m * N + n] = v00;       C[(size_t)m * N + n + 1] = v01;
  C[(size_t)(m + 1) * N + n] = v10; C[(size_t)(m + 1) * N + n + 1] = v11;
}

// z_mean/z_log_var = h @ Wmu^T/Wlv^T + b; write outputs; z -> dz[0:64]
__global__ __launch_bounds__(128) void mulv_z_kernel(const float* __restrict__ h,
    const float* __restrict__ Wmu, const float* __restrict__ bmu,
    const float* __restrict__ Wlv, const float* __restrict__ blv,
    const float* __restrict__ eps, float* __restrict__ out, float* __restrict__ dz) {
  __shared__ __align__(16) float hs[512];
  __shared__ float zms[64], zlvs[64];
  int b = blockIdx.x, t = threadIdx.x;
  for (int i = t; i < 512; i += 128) hs[i] = h[b * 512 + i];
  __syncthreads();
  const float* Wr = (t < 64) ? (Wmu + (size_t)t * 512) : (Wlv + (size_t)(t - 64) * 512);
  float bias = (t < 64) ? bmu[t] : blv[t - 64];
  const float4* w4 = (const float4*)Wr;
  const float4* h4 = (const float4*)hs;
  float a0 = 0.f, a1 = 0.f, a2 = 0.f, a3 = 0.f;
  #pragma unroll 4
  for (int i = 0; i < 128; ++i) {
    float4 w = w4[i], hv = h4[i];
    a0 = fmaf(w.x, hv.x, a0); a1 = fmaf(w.y, hv.y, a1);
    a2 = fmaf(w.z, hv.z, a2); a3 = fmaf(w.w, hv.w, a3);
  }
  float acc = (a0 + a1) + (a2 + a3) + bias;
  if (t < 64) { out[OUT_ZM + b * 64 + t] = acc; zms[t] = acc; }
  else        { out[OUT_ZLV + b * 64 + (t - 64)] = acc; zlvs[t - 64] = acc; }
  __syncthreads();
  if (t < 64) {
    // z = z_mean + eps * exp(0.5*z_log_var); exp(0.5v) = exp2(0.5*log2e*v)
    float zv = fmaf(eps[b * 64 + t], exp2f(0.7213475204444817f * zlvs[t]), zms[t]);
    dz[b * 1104 + t] = zv;
  }
}

// Per (b,k): online softmax over 50000 items: max, argmax, sum(exp), slate prob
__global__ __launch_bounds__(256, 1) void score_kernel(const float* __restrict__ rx,
    const float* __restrict__ emb, const int* __restrict__ slate, float* __restrict__ out) {
  constexpr float LOG2E = 1.44269504088896340736f;
  __shared__ __align__(16) float rxs[160];
  __shared__ float pm[4][10], ps[4][10];
  __shared__ int pa[4][10];
  int b = blockIdx.x, t = threadIdx.x;
  if (t < 160) rxs[t] = rx[b * 160 + t];
  __syncthreads();
  float m[10], s[10];
  int am[10];
  #pragma unroll
  for (int k = 0; k < 10; ++k) { m[k] = -3.402823466e38f; s[k] = 0.f; am[k] = 0; }

  float4 e0, e1, e2, e3;
  int n = t;
  {
    const float4* p = (const float4*)(emb + (size_t)n * 16);
    e0 = p[0]; e1 = p[1]; e2 = p[2]; e3 = p[3];
  }
  for (; n < NITEMS; n += 256) {
    int nn = n + 256;
    float4 f0 = make_float4(0.f,0.f,0.f,0.f), f1 = f0, f2 = f0, f3 = f0;
    if (nn < NITEMS) {
      const float4* p = (const float4*)(emb + (size_t)nn * 16);
      f0 = p[0]; f1 = p[1]; f2 = p[2]; f3 = p[3];
    }
    #pragma unroll
    for (int k = 0; k < 10; ++k) {
      const float4 r0 = *(const float4*)(rxs + k * 16);
      const float4 r1 = *(const float4*)(rxs + k * 16 + 4);
      const float4 r2 = *(const float4*)(rxs + k * 16 + 8);
      const float4 r3 = *(const float4*)(rxs + k * 16 + 12);
      float x0 = fmaf(e0.w, r0.w, fmaf(e0.z, r0.z, fmaf(e0.y, r0.y, e0.x * r0.x)));
      float x1 = fmaf(e1.w, r1.w, fmaf(e1.z, r1.z, fmaf(e1.y, r1.y, e1.x * r1.x)));
      float x2 = fmaf(e2.w, r2.w, fmaf(e2.z, r2.z, fmaf(e2.y, r2.y, e2.x * r2.x)));
      float x3 = fmaf(e3.w, r3.w, fmaf(e3.z, r3.z, fmaf(e3.y, r3.y, e3.x * r3.x)));
      float x = (x0 + x1) + (x2 + x3);
      float mn = fmaxf(m[k], x);
      float w = exp2f(LOG2E * (m[k] - mn));
      float d = exp2f(LOG2E * (x - mn));
      s[k] = fmaf(s[k], w, d);
      if (x > m[k]) am[k] = n;
      m[k] = mn;
    }
    e0 = f0; e1 = f1; e2 = f2; e3 = f3;
  }
  // wave reduce (64 lanes)
  #pragma unroll
  for (int off = 32; off > 0; off >>= 1) {
    #pragma unroll
    for (int k = 0; k < 10; ++k) {
      float om = __shfl_down(m[k], off);
      float os = __shfl_down(s[k], off);
      int oa = __shfl_down(am[k], off);
      float M2 = fmaxf(m[k], om);
      s[k] = s[k] * exp2f(LOG2E * (m[k] - M2)) + os * exp2f(LOG2E * (om - M2));
      am[k] = (om > m[k]) ? oa : ((m[k] > om) ? am[k] : (am[k] < oa ? am[k] : oa));
      m[k] = M2;
    }
  }
  int lane = t & 63, wv = t >> 6;
  if (lane == 0) {
    #pragma unroll
    for (int k = 0; k < 10; ++k) { pm[wv][k] = m[k]; ps[wv][k] = s[k]; pa[wv][k] = am[k]; }
  }
  __syncthreads();
  if (t < 10) {
    int k = t;
    float M = pm[0][k], S = ps[0][k];
    int AM = pa[0][k];
    #pragma unroll
    for (int w = 1; w < 4; ++w) {
      float m2 = pm[w][k];
      float M2 = fmaxf(M, m2);
      S = S * exp2f(LOG2E * (M - M2)) + ps[w][k] * exp2f(LOG2E * (m2 - M2));
      AM = (m2 > M) ? pa[w][k] : ((M > m2) ? AM : (AM < pa[w][k] ? AM : pa[w][k]));
      M = M2;
    }
    int it = slate[b * 10 + k];
    const float* er = emb + (size_t)it * 16;
    float xs = 0.f;
    #pragma unroll
    for (int e = 0; e < 16; ++e) xs = fmaf(rxs[k * 16 + e], er[e], xs);
    out[OUT_RS + b * 10 + k] = (float)AM;
    out[OUT_RR + b * 10 + k] = exp2f(LOG2E * (xs - M)) / S;
  }
}

extern "C" void kernel_launch(void* const* d_in, const int* in_sizes, int n_in,
                              void* d_out, int out_size, void* d_ws, size_t ws_size,
                              hipStream_t stream) {
  const int* user_repr = (const int*)d_in[0];
  const int* slate = (const int*)d_in[1];
  const float* resp = (const float*)d_in[2];
  const float* eps = (const float*)d_in[3];
  const float* emb = (const float*)d_in[4];
  const float* W_enc = (const float*)d_in[5];
  const float* b_enc = (const float*)d_in[6];
  const float* W_mu = (const float*)d_in[7];
  const float* b_mu = (const float*)d_in[8];
  const float* W_lv = (const float*)d_in[9];
  const float* b_lv = (const float*)d_in[10];
  const float* W_d1 = (const float*)d_in[11];
  const float* b_d1 = (const float*)d_in[12];
  const float* W_d2 = (const float*)d_in[13];
  const float* b_d2 = (const float*)d_in[14];
  float* out = (float*)d_out;
  float* ws = (float*)d_ws;

  float* usum = ws + WS_USUM;
  float* cnt  = ws + WS_CNT;
  float* x    = ws + WS_X;
  float* h    = ws + WS_H;
  float* dz   = ws + WS_DZ;
  float* dh   = ws + WS_DH;
  float* rx   = ws + WS_RX;

  zero_kernel<<<17, 256, 0, stream>>>(usum, 4352);  // usum + cnt
  pool_kernel<<<dim3(256, 8), 256, 0, stream>>>(user_repr, emb, usum, cnt);
  build_x_kernel<<<256, 256, 0, stream>>>(slate, resp, emb, usum, cnt, x, dz);
  gemm_bias<true><<<dim3(16, 8), 256, 0, stream>>>(x, W_enc, b_enc, h, 256, 512, 1200);
  mulv_z_kernel<<<256, 128, 0, stream>>>(h, W_mu, b_mu, W_lv, b_lv, eps, out, dz);
  gemm_bias<true><<<dim3(16, 8), 256, 0, stream>>>(dz, W_d1, b_d1, dh, 256, 512, 1104);
  gemm_bias<true><<<dim3(5, 8), 256, 0, stream>>>(dh, W_d2, b_d2, rx, 256, 160, 512);
  score_kernel<<<256, 256, 0, stream>>>(rx, emb, slate, out);
}

// Round 2
// 403.665 us; speedup vs baseline: 1.2473x; 1.2473x over previous
//
#include <hip/hip_runtime.h>

// Problem constants
#define NITEMS 50000
#define EMBD   16
#define NSLATE 10
#define HIDD   512
#define LATD   64
#define RESPD  1024
#define BATCH  256
#define NCHUNK 8
#define CHUNK  6250   // NITEMS / NCHUNK

// d_out layout (float): z_mean[256*64] | z_log_var[256*64] | recon_slate[256*10] | recon_resp[256*10]
#define OUT_ZM 0
#define OUT_ZLV 16384
#define OUT_RS 32768
#define OUT_RR 35328

// ws layout (floats):
#define WS_USUM 0        // 4096
#define WS_CNT  4096     // 256
#define WS_X    4352     // 256*1200 = 307200
#define WS_H    311552   // 131072
#define WS_DZ   442624   // 256*1104 = 282624
#define WS_DH   725248   // 131072
#define WS_RX   856320   // 40960
#define WS_PART 897280   // 4*256*512 = 524288 (gemm partials, reused per gemm)
#define WS_SPM  1421568  // 256*8*10 = 20480
#define WS_SPS  1442048  // 20480
#define WS_SPA  1462528  // 20480 (int)
// total 1483008 floats = 5.93 MB

__global__ __launch_bounds__(256) void zero_kernel(float* __restrict__ p, int n) {
  int i = blockIdx.x * 256 + threadIdx.x;
  if (i < n) p[i] = 0.0f;
}

// user_sum[b][e] += sum_n u[b][n]*emb[n][e]; cnt[b] += sum_n u[b][n]
__global__ __launch_bounds__(256) void pool_kernel(const int* __restrict__ u,
    const float* __restrict__ emb, float* __restrict__ usum, float* __restrict__ cnt) {
  int b = blockIdx.x;
  int n0 = blockIdx.y * CHUNK;
  int n1 = n0 + CHUNK; if (n1 > NITEMS) n1 = NITEMS;
  float acc[16];
  #pragma unroll
  for (int i = 0; i < 16; ++i) acc[i] = 0.0f;
  float c = 0.0f;
  const int* ub = u + b * NITEMS;
  for (int n = n0 + (int)threadIdx.x; n < n1; n += 256) {
    int uv = ub[n];
    if (uv) {
      const float4* e4 = (const float4*)(emb + n * 16);
      float4 a = e4[0], bb = e4[1], cc = e4[2], dd = e4[3];
      acc[0] += a.x;  acc[1] += a.y;  acc[2] += a.z;  acc[3] += a.w;
      acc[4] += bb.x; acc[5] += bb.y; acc[6] += bb.z; acc[7] += bb.w;
      acc[8] += cc.x; acc[9] += cc.y; acc[10] += cc.z; acc[11] += cc.w;
      acc[12] += dd.x; acc[13] += dd.y; acc[14] += dd.z; acc[15] += dd.w;
      c += 1.0f;
    }
  }
  #pragma unroll
  for (int off = 32; off > 0; off >>= 1) {
    #pragma unroll
    for (int i = 0; i < 16; ++i) acc[i] += __shfl_down(acc[i], off);
    c += __shfl_down(c, off);
  }
  if ((threadIdx.x & 63) == 0) {
    #pragma unroll
    for (int i = 0; i < 16; ++i) atomicAdd(&usum[b * 16 + i], acc[i]);
    atomicAdd(&cnt[b], c);
  }
}

// user = usum/cnt; x = [slate_vec(160) | user(16) | resp(1024)]; dz[64:1104] = [user | resp]
__global__ __launch_bounds__(256) void build_x_kernel(const int* __restrict__ slate,
    const float* __restrict__ resp, const float* __restrict__ emb,
    const float* __restrict__ usum, const float* __restrict__ cnt,
    float* __restrict__ x, float* __restrict__ dz) {
  int b = blockIdx.x, t = threadIdx.x;
  float inv = 1.0f / cnt[b];
  if (t < 16) {
    float uv = usum[b * 16 + t] * inv;
    x[b * 1200 + 160 + t] = uv;
    dz[b * 1104 + 64 + t] = uv;
  }
  if (t >= 32 && t < 192) {
    int i = t - 32;
    int k = i >> 4, e = i & 15;
    int it = slate[b * 10 + k];
    x[b * 1200 + i] = emb[it * 16 + e];
  }
  for (int i = t; i < 1024; i += 256) {
    float r = resp[b * 1024 + i];
    x[b * 1200 + 176 + i] = r;
    dz[b * 1104 + 80 + i] = r;
  }
}

// Partial GEMM: P[z][M,N] = A[M, ks:ke] @ B[N, ks:ke]^T  (32x32 tile, 2x2 microtile)
__global__ __launch_bounds__(256) void gemm_part(const float* __restrict__ A,
    const float* __restrict__ B, float* __restrict__ P, int M, int N, int K, int kChunk) {
  __shared__ float As[32][33];
  __shared__ float Bs[32][33];
  int tid = threadIdx.x;
  int tx = tid & 15, ty = tid >> 4;
  int m0 = blockIdx.y * 32, n0 = blockIdx.x * 32;
  int ks = blockIdx.z * kChunk;
  int ke = ks + kChunk; if (ke > K) ke = K;
  int lr = tid >> 3;          // 0..31
  int lc = (tid & 7) * 4;     // 0,4,..,28
  float acc00 = 0.f, acc01 = 0.f, acc10 = 0.f, acc11 = 0.f;
  for (int k0 = ks; k0 < ke; k0 += 32) {
    float4 av = make_float4(0.f, 0.f, 0.f, 0.f);
    float4 bv = make_float4(0.f, 0.f, 0.f, 0.f);
    if (k0 + lc < ke) {   // kChunk%4==0 so this covers all 4 lanes' floats
      av = *(const float4*)(A + (size_t)(m0 + lr) * K + k0 + lc);
      bv = *(const float4*)(B + (size_t)(n0 + lr) * K + k0 + lc);
    }
    As[lr][lc] = av.x; As[lr][lc + 1] = av.y; As[lr][lc + 2] = av.z; As[lr][lc + 3] = av.w;
    Bs[lr][lc] = bv.x; Bs[lr][lc + 1] = bv.y; Bs[lr][lc + 2] = bv.z; Bs[lr][lc + 3] = bv.w;
    __syncthreads();
    #pragma unroll
    for (int kk = 0; kk < 32; ++kk) {
      float a0 = As[2 * ty][kk], a1 = As[2 * ty + 1][kk];
      float b0 = Bs[2 * tx][kk], b1 = Bs[2 * tx + 1][kk];
      acc00 = fmaf(a0, b0, acc00); acc01 = fmaf(a0, b1, acc01);
      acc10 = fmaf(a1, b0, acc10); acc11 = fmaf(a1, b1, acc11);
    }
    __syncthreads();
  }
  int m = m0 + 2 * ty, n = n0 + 2 * tx;
  float* Pz = P + (size_t)blockIdx.z * M * N;
  Pz[(size_t)m * N + n] = acc00;       Pz[(size_t)m * N + n + 1] = acc01;
  Pz[(size_t)(m + 1) * N + n] = acc10; Pz[(size_t)(m + 1) * N + n + 1] = acc11;
}

// C[i] = act(sum_s P[s][i] + bias[i%N])
template <bool RELU>
__global__ __launch_bounds__(256) void reduce_bias(const float* __restrict__ P,
    const float* __restrict__ bias, float* __restrict__ C, int MN, int N, int S) {
  int i = blockIdx.x * 256 + threadIdx.x;
  if (i >= MN) return;
  float a = bias[i % N];
  for (int s = 0; s < S; ++s) a += P[(size_t)s * MN + i];
  if (RELU) a = fmaxf(a, 0.f);
  C[i] = a;
}

// z_mean/z_log_var = h @ Wmu^T/Wlv^T + b; write outputs; z -> dz[0:64]
__global__ __launch_bounds__(128) void mulv_z_kernel(const float* __restrict__ h,
    const float* __restrict__ Wmu, const float* __restrict__ bmu,
    const float* __restrict__ Wlv, const float* __restrict__ blv,
    const float* __restrict__ eps, float* __restrict__ out, float* __restrict__ dz) {
  __shared__ __align__(16) float hs[512];
  __shared__ float zms[64], zlvs[64];
  int b = blockIdx.x, t = threadIdx.x;
  for (int i = t; i < 512; i += 128) hs[i] = h[b * 512 + i];
  __syncthreads();
  const float* Wr = (t < 64) ? (Wmu + (size_t)t * 512) : (Wlv + (size_t)(t - 64) * 512);
  float bias = (t < 64) ? bmu[t] : blv[t - 64];
  const float4* w4 = (const float4*)Wr;
  const float4* h4 = (const float4*)hs;
  float a0 = 0.f, a1 = 0.f, a2 = 0.f, a3 = 0.f;
  #pragma unroll 4
  for (int i = 0; i < 128; ++i) {
    float4 w = w4[i], hv = h4[i];
    a0 = fmaf(w.x, hv.x, a0); a1 = fmaf(w.y, hv.y, a1);
    a2 = fmaf(w.z, hv.z, a2); a3 = fmaf(w.w, hv.w, a3);
  }
  float acc = (a0 + a1) + (a2 + a3) + bias;
  if (t < 64) { out[OUT_ZM + b * 64 + t] = acc; zms[t] = acc; }
  else        { out[OUT_ZLV + b * 64 + (t - 64)] = acc; zlvs[t - 64] = acc; }
  __syncthreads();
  if (t < 64) {
    float zv = fmaf(eps[b * 64 + t], exp2f(0.7213475204444817f * zlvs[t]), zms[t]);
    dz[b * 1104 + t] = zv;
  }
}

// Per (b, chunk): online softmax partials over 6250 items for all 10 slate positions.
// rxs hoisted to registers (160 VGPRs) => zero LDS traffic in the hot loop.
__global__ __launch_bounds__(256, 2) void score_part(const float* __restrict__ rx,
    const float* __restrict__ emb, float* __restrict__ pmg, float* __restrict__ psg,
    int* __restrict__ pag) {
  constexpr float LOG2E = 1.44269504088896340736f;
  __shared__ __align__(16) float rxs[160];
  __shared__ float wm[4][10], wsum[4][10];
  __shared__ int wa[4][10];
  int b = blockIdx.x, c = blockIdx.y, t = threadIdx.x;
  if (t < 160) rxs[t] = rx[b * 160 + t];
  __syncthreads();
  float4 r0[10], r1[10], r2[10], r3[10];
  #pragma unroll
  for (int k = 0; k < 10; ++k) {
    const float4* p = (const float4*)(rxs + k * 16);
    r0[k] = p[0]; r1[k] = p[1]; r2[k] = p[2]; r3[k] = p[3];
  }
  float m[10], s[10];
  int am[10];
  #pragma unroll
  for (int k = 0; k < 10; ++k) { m[k] = -3.402823466e38f; s[k] = 0.f; am[k] = 0; }

  int nBase = c * CHUNK;
  int nEnd = nBase + CHUNK;
  int n = nBase + t;
  float4 e0, e1, e2, e3;
  {
    const float4* p = (const float4*)(emb + (size_t)n * 16);
    e0 = p[0]; e1 = p[1]; e2 = p[2]; e3 = p[3];
  }
  #pragma unroll 1
  for (; n < nEnd; n += 256) {
    int nn = n + 256;
    float4 f0 = make_float4(0.f,0.f,0.f,0.f), f1 = f0, f2 = f0, f3 = f0;
    if (nn < nEnd) {
      const float4* p = (const float4*)(emb + (size_t)nn * 16);
      f0 = p[0]; f1 = p[1]; f2 = p[2]; f3 = p[3];
    }
    #pragma unroll
    for (int k = 0; k < 10; ++k) {
      float x0 = fmaf(e0.w, r0[k].w, fmaf(e0.z, r0[k].z, fmaf(e0.y, r0[k].y, e0.x * r0[k].x)));
      float x1 = fmaf(e1.w, r1[k].w, fmaf(e1.z, r1[k].z, fmaf(e1.y, r1[k].y, e1.x * r1[k].x)));
      float x2 = fmaf(e2.w, r2[k].w, fmaf(e2.z, r2[k].z, fmaf(e2.y, r2[k].y, e2.x * r2[k].x)));
      float x3 = fmaf(e3.w, r3[k].w, fmaf(e3.z, r3[k].z, fmaf(e3.y, r3[k].y, e3.x * r3[k].x)));
      float x = (x0 + x1) + (x2 + x3);
      float mn = fmaxf(m[k], x);
      float w = exp2f(LOG2E * (m[k] - mn));
      float d = exp2f(LOG2E * (x - mn));
      s[k] = fmaf(s[k], w, d);
      if (x > m[k]) am[k] = n;
      m[k] = mn;
    }
    e0 = f0; e1 = f1; e2 = f2; e3 = f3;
  }
  // wave reduce (64 lanes); lower index wins ties
  #pragma unroll
  for (int off = 32; off > 0; off >>= 1) {
    #pragma unroll
    for (int k = 0; k < 10; ++k) {
      float om = __shfl_down(m[k], off);
      float os = __shfl_down(s[k], off);
      int oa = __shfl_down(am[k], off);
      float M2 = fmaxf(m[k], om);
      s[k] = s[k] * exp2f(LOG2E * (m[k] - M2)) + os * exp2f(LOG2E * (om - M2));
      am[k] = (om > m[k]) ? oa : ((m[k] > om) ? am[k] : (am[k] < oa ? am[k] : oa));
      m[k] = M2;
    }
  }
  int lane = t & 63, wv = t >> 6;
  if (lane == 0) {
    #pragma unroll
    for (int k = 0; k < 10; ++k) { wm[wv][k] = m[k]; wsum[wv][k] = s[k]; wa[wv][k] = am[k]; }
  }
  __syncthreads();
  if (t < 10) {
    int k = t;
    float M = wm[0][k], S = wsum[0][k];
    int AM = wa[0][k];
    #pragma unroll
    for (int w = 1; w < 4; ++w) {
      float m2 = wm[w][k];
      float M2 = fmaxf(M, m2);
      S = S * exp2f(LOG2E * (M - M2)) + wsum[w][k] * exp2f(LOG2E * (m2 - M2));
      AM = (m2 > M) ? wa[w][k] : ((M > m2) ? AM : (AM < wa[w][k] ? AM : wa[w][k]));
      M = M2;
    }
    int idx = (b * NCHUNK + c) * 10 + k;
    pmg[idx] = M; psg[idx] = S; pag[idx] = AM;
  }
}

// Combine 8 chunk-partials per (b,k); compute argmax + slate prob.
__global__ __launch_bounds__(256) void score_final(const float* __restrict__ pmg,
    const float* __restrict__ psg, const int* __restrict__ pag,
    const float* __restrict__ rx, const float* __restrict__ emb,
    const int* __restrict__ slate, float* __restrict__ out) {
  constexpr float LOG2E = 1.44269504088896340736f;
  int tid = blockIdx.x * 256 + threadIdx.x;
  if (tid >= BATCH * 10) return;
  int b = tid / 10, k = tid % 10;
  int base = b * NCHUNK * 10 + k;
  float M = pmg[base], S = psg[base];
  int AM = pag[base];
  #pragma unroll
  for (int c = 1; c < NCHUNK; ++c) {
    float m2 = pmg[base + c * 10];
    float M2 = fmaxf(M, m2);
    S = S * exp2f(LOG2E * (M - M2)) + psg[base + c * 10] * exp2f(LOG2E * (m2 - M2));
    int oa = pag[base + c * 10];
    AM = (m2 > M) ? oa : ((M > m2) ? AM : (AM < oa ? AM : oa));
    M = M2;
  }
  int it = slate[b * 10 + k];
  const float* er = emb + (size_t)it * 16;
  const float* rr = rx + b * 160 + k * 16;
  float xs = 0.f;
  #pragma unroll
  for (int e = 0; e < 16; ++e) xs = fmaf(rr[e], er[e], xs);
  out[OUT_RS + b * 10 + k] = (float)AM;
  out[OUT_RR + b * 10 + k] = exp2f(LOG2E * (xs - M)) / S;
}

extern "C" void kernel_launch(void* const* d_in, const int* in_sizes, int n_in,
                              void* d_out, int out_size, void* d_ws, size_t ws_size,
                              hipStream_t stream) {
  const int* user_repr = (const int*)d_in[0];
  const int* slate = (const int*)d_in[1];
  const float* resp = (const float*)d_in[2];
  const float* eps = (const float*)d_in[3];
  const float* emb = (const float*)d_in[4];
  const float* W_enc = (const float*)d_in[5];
  const float* b_enc = (const float*)d_in[6];
  const float* W_mu = (const float*)d_in[7];
  const float* b_mu = (const float*)d_in[8];
  const float* W_lv = (const float*)d_in[9];
  const float* b_lv = (const float*)d_in[10];
  const float* W_d1 = (const float*)d_in[11];
  const float* b_d1 = (const float*)d_in[12];
  const float* W_d2 = (const float*)d_in[13];
  const float* b_d2 = (const float*)d_in[14];
  float* out = (float*)d_out;
  float* ws = (float*)d_ws;

  float* usum = ws + WS_USUM;
  float* cnt  = ws + WS_CNT;
  float* x    = ws + WS_X;
  float* h    = ws + WS_H;
  float* dz   = ws + WS_DZ;
  float* dh   = ws + WS_DH;
  float* rx   = ws + WS_RX;
  float* part = ws + WS_PART;
  float* spm  = ws + WS_SPM;
  float* sps  = ws + WS_SPS;
  int*   spa  = (int*)(ws + WS_SPA);

  zero_kernel<<<17, 256, 0, stream>>>(usum, 4352);  // usum + cnt
  pool_kernel<<<dim3(256, 8), 256, 0, stream>>>(user_repr, emb, usum, cnt);
  build_x_kernel<<<256, 256, 0, stream>>>(slate, resp, emb, usum, cnt, x, dz);

  gemm_part<<<dim3(16, 8, 4), 256, 0, stream>>>(x, W_enc, part, 256, 512, 1200, 300);
  reduce_bias<true><<<512, 256, 0, stream>>>(part, b_enc, h, 131072, 512, 4);
  mulv_z_kernel<<<256, 128, 0, stream>>>(h, W_mu, b_mu, W_lv, b_lv, eps, out, dz);
  gemm_part<<<dim3(16, 8, 4), 256, 0, stream>>>(dz, W_d1, part, 256, 512, 1104, 276);
  reduce_bias<true><<<512, 256, 0, stream>>>(part, b_d1, dh, 131072, 512, 4);
  gemm_part<<<dim3(5, 8, 4), 256, 0, stream>>>(dh, W_d2, part, 256, 160, 512, 128);
  reduce_bias<true><<<160, 256, 0, stream>>>(part, b_d2, rx, 40960, 160, 4);

  score_part<<<dim3(256, 8), 256, 0, stream>>>(rx, emb, spm, sps, spa);
  score_final<<<10, 256, 0, stream>>>(spm, sps, spa, rx, emb, slate, out);
}

// Round 3
// 360.549 us; speedup vs baseline: 1.3965x; 1.1196x over previous
//
#include <hip/hip_runtime.h>

// Problem constants
#define NITEMS 50000
#define EMBD   16
#define NSLATE 10
#define HIDD   512
#define LATD   64
#define RESPD  1024
#define BATCH  256
#define NCHUNK 8
#define CHUNK  6250   // NITEMS / NCHUNK
#define LOG2E  1.44269504088896340736f

// d_out layout (float): z_mean[256*64] | z_log_var[256*64] | recon_slate[256*10] | recon_resp[256*10]
#define OUT_ZM 0
#define OUT_ZLV 16384
#define OUT_RS 32768
#define OUT_RR 35328

// ws layout (floats):
#define WS_USUM 0        // 4096
#define WS_CNT  4096     // 256
#define WS_X    4352     // 256*1200 = 307200
#define WS_DZ   311552   // 256*1104 = 282624
#define WS_DH   594176   // 131072
#define WS_RX   725248   // 40960
#define WS_PART 766208   // 4*256*512 = 524288 (gemm split-K partials, reused)
#define WS_SPM  1290496  // 256*8*10 = 20480
#define WS_SPS  1310976  // 20480
#define WS_SPA  1331456  // 20480 (int)
// total 1351936 floats = 5.41 MB

__global__ __launch_bounds__(256) void zero_kernel(float* __restrict__ p, int n) {
  int i = blockIdx.x * 256 + threadIdx.x;
  if (i < n) p[i] = 0.0f;
}

// user_sum[b][e] += sum_n u[b][n]*emb[n][e]; cnt[b] += sum_n u[b][n]
__global__ __launch_bounds__(256) void pool_kernel(const int* __restrict__ u,
    const float* __restrict__ emb, float* __restrict__ usum, float* __restrict__ cnt) {
  int b = blockIdx.x;
  int n0 = blockIdx.y * CHUNK;
  int n1 = n0 + CHUNK; if (n1 > NITEMS) n1 = NITEMS;
  float acc[16];
  #pragma unroll
  for (int i = 0; i < 16; ++i) acc[i] = 0.0f;
  float c = 0.0f;
  const int* ub = u + b * NITEMS;
  for (int n = n0 + (int)threadIdx.x; n < n1; n += 256) {
    int uv = ub[n];
    if (uv) {
      const float4* e4 = (const float4*)(emb + n * 16);
      float4 a = e4[0], bb = e4[1], cc = e4[2], dd = e4[3];
      acc[0] += a.x;  acc[1] += a.y;  acc[2] += a.z;  acc[3] += a.w;
      acc[4] += bb.x; acc[5] += bb.y; acc[6] += bb.z; acc[7] += bb.w;
      acc[8] += cc.x; acc[9] += cc.y; acc[10] += cc.z; acc[11] += cc.w;
      acc[12] += dd.x; acc[13] += dd.y; acc[14] += dd.z; acc[15] += dd.w;
      c += 1.0f;
    }
  }
  #pragma unroll
  for (int off = 32; off > 0; off >>= 1) {
    #pragma unroll
    for (int i = 0; i < 16; ++i) acc[i] += __shfl_down(acc[i], off);
    c += __shfl_down(c, off);
  }
  if ((threadIdx.x & 63) == 0) {
    #pragma unroll
    for (int i = 0; i < 16; ++i) atomicAdd(&usum[b * 16 + i], acc[i]);
    atomicAdd(&cnt[b], c);
  }
}

// user = usum/cnt; x = [slate_vec(160) | user(16) | resp(1024)]; dz[64:1104] = [user | resp]
__global__ __launch_bounds__(256) void build_x_kernel(const int* __restrict__ slate,
    const float* __restrict__ resp, const float* __restrict__ emb,
    const float* __restrict__ usum, const float* __restrict__ cnt,
    float* __restrict__ x, float* __restrict__ dz) {
  int b = blockIdx.x, t = threadIdx.x;
  float inv = 1.0f / cnt[b];
  if (t < 16) {
    float uv = usum[b * 16 + t] * inv;
    x[b * 1200 + 160 + t] = uv;
    dz[b * 1104 + 64 + t] = uv;
  }
  if (t >= 32 && t < 192) {
    int i = t - 32;
    int k = i >> 4, e = i & 15;
    int it = slate[b * 10 + k];
    x[b * 1200 + i] = emb[it * 16 + e];
  }
  for (int i = t; i < 1024; i += 256) {
    float r = resp[b * 1024 + i];
    x[b * 1200 + 176 + i] = r;
    dz[b * 1104 + 80 + i] = r;
  }
}

// Split-K partial GEMM: P[z][M,N] = A[M,ks:ke] @ B[N,ks:ke]^T
// 64x64 tile, 256 threads, 4x4 microtile, BK=16, transposed LDS stage so the
// inner loop is 2x ds_read_b128 per 16 FMA.
__global__ __launch_bounds__(256) void gemm64(const float* __restrict__ A,
    const float* __restrict__ B, float* __restrict__ P, int M, int N, int K, int kChunk) {
  __shared__ float As[16][68];  // As[kk][m]
  __shared__ float Bs[16][68];  // Bs[kk][n]
  int tid = threadIdx.x;
  int m0 = blockIdx.y * 64, n0 = blockIdx.x * 64;
  int ks = blockIdx.z * kChunk;
  int ke = ks + kChunk; if (ke > K) ke = K;
  int sr = tid >> 2;          // 0..63: row within tile
  int sc = (tid & 3) * 4;     // 0,4,8,12: kk offset
  int tx = tid & 15, ty = tid >> 4;
  float acc[4][4];
  #pragma unroll
  for (int i = 0; i < 4; ++i)
    #pragma unroll
    for (int j = 0; j < 4; ++j) acc[i][j] = 0.f;
  for (int k0 = ks; k0 < ke; k0 += 16) {
    float4 av = make_float4(0.f, 0.f, 0.f, 0.f);
    float4 bv = make_float4(0.f, 0.f, 0.f, 0.f);
    if (k0 + sc < ke)  // K chunks are multiples of 4, so whole float4 in-range
      av = *(const float4*)(A + (size_t)(m0 + sr) * K + k0 + sc);
    if (k0 + sc < ke && n0 + sr < N)
      bv = *(const float4*)(B + (size_t)(n0 + sr) * K + k0 + sc);
    __syncthreads();
    As[sc][sr] = av.x; As[sc + 1][sr] = av.y; As[sc + 2][sr] = av.z; As[sc + 3][sr] = av.w;
    Bs[sc][sr] = bv.x; Bs[sc + 1][sr] = bv.y; Bs[sc + 2][sr] = bv.z; Bs[sc + 3][sr] = bv.w;
    __syncthreads();
    #pragma unroll
    for (int kk = 0; kk < 16; ++kk) {
      float4 a4 = *(const float4*)&As[kk][4 * ty];
      float4 b4 = *(const float4*)&Bs[kk][4 * tx];
      float a[4] = {a4.x, a4.y, a4.z, a4.w};
      float b[4] = {b4.x, b4.y, b4.z, b4.w};
      #pragma unroll
      for (int i = 0; i < 4; ++i)
        #pragma unroll
        for (int j = 0; j < 4; ++j) acc[i][j] = fmaf(a[i], b[j], acc[i][j]);
    }
  }
  float* Pz = P + (size_t)blockIdx.z * M * N;
  #pragma unroll
  for (int i = 0; i < 4; ++i) {
    int m = m0 + 4 * ty + i, n = n0 + 4 * tx;
    if (n < N) {
      float4 v = make_float4(acc[i][0], acc[i][1], acc[i][2], acc[i][3]);
      *(float4*)(Pz + (size_t)m * N + n) = v;
    }
  }
}

// C[i] = act(sum_s P[s][i] + bias[i%N])
template <bool RELU>
__global__ __launch_bounds__(256) void reduce_bias(const float* __restrict__ P,
    const float* __restrict__ bias, float* __restrict__ C, int MN, int N, int S) {
  int i = blockIdx.x * 256 + threadIdx.x;
  if (i >= MN) return;
  float a = bias[i % N];
  for (int s = 0; s < S; ++s) a += P[(size_t)s * MN + i];
  if (RELU) a = fmaxf(a, 0.f);
  C[i] = a;
}

// h = relu(sum_s part[s] + b_enc) computed in-kernel; z_mean/z_log_var; z -> dz[0:64]
__global__ __launch_bounds__(128) void mulv_z_kernel(const float* __restrict__ part,
    const float* __restrict__ benc,
    const float* __restrict__ Wmu, const float* __restrict__ bmu,
    const float* __restrict__ Wlv, const float* __restrict__ blv,
    const float* __restrict__ eps, float* __restrict__ out, float* __restrict__ dz) {
  __shared__ __align__(16) float hs[512];
  __shared__ float zms[64], zlvs[64];
  int b = blockIdx.x, t = threadIdx.x;
  for (int i = t; i < 512; i += 128) {
    float a = benc[i];
    #pragma unroll
    for (int s = 0; s < 4; ++s) a += part[(size_t)s * 131072 + b * 512 + i];
    hs[i] = fmaxf(a, 0.f);
  }
  __syncthreads();
  const float* Wr = (t < 64) ? (Wmu + (size_t)t * 512) : (Wlv + (size_t)(t - 64) * 512);
  float bias = (t < 64) ? bmu[t] : blv[t - 64];
  const float4* w4 = (const float4*)Wr;
  const float4* h4 = (const float4*)hs;
  float a0 = 0.f, a1 = 0.f, a2 = 0.f, a3 = 0.f;
  #pragma unroll 4
  for (int i = 0; i < 128; ++i) {
    float4 w = w4[i], hv = h4[i];
    a0 = fmaf(w.x, hv.x, a0); a1 = fmaf(w.y, hv.y, a1);
    a2 = fmaf(w.z, hv.z, a2); a3 = fmaf(w.w, hv.w, a3);
  }
  float acc = (a0 + a1) + (a2 + a3) + bias;
  if (t < 64) { out[OUT_ZM + b * 64 + t] = acc; zms[t] = acc; }
  else        { out[OUT_ZLV + b * 64 + (t - 64)] = acc; zlvs[t - 64] = acc; }
  __syncthreads();
  if (t < 64) {
    float zv = fmaf(eps[b * 64 + t], exp2f(0.7213475204444817f * zlvs[t]), zms[t]);
    dz[b * 1104 + t] = zv;
  }
}

// Per (b, chunk): online softmax partials in log2 domain.
// rx pre-scaled by log2(e); single raw v_exp_f32 per (item,k) via
// alpha = exp2(-|x - m|), s = (x>m) ? s*alpha + 1 : s + alpha.
__global__ __launch_bounds__(256, 2) void score_part(const float* __restrict__ rx,
    const float* __restrict__ emb, float* __restrict__ pmg, float* __restrict__ psg,
    int* __restrict__ pag) {
  __shared__ __align__(16) float rxs[160];
  __shared__ float wm[4][10], wsum[4][10];
  __shared__ int wa[4][10];
  int b = blockIdx.x, c = blockIdx.y, t = threadIdx.x;
  if (t < 160) rxs[t] = rx[b * 160 + t] * LOG2E;  // log2 domain
  __syncthreads();
  float m[10], s[10];
  int am[10];
  #pragma unroll
  for (int k = 0; k < 10; ++k) { m[k] = -3.402823466e38f; s[k] = 0.f; am[k] = 0; }

  int nBase = c * CHUNK;
  int nEnd = nBase + CHUNK;
  int n = nBase + t;
  float4 e0, e1, e2, e3;
  {
    const float4* p = (const float4*)(emb + (size_t)n * 16);
    e0 = p[0]; e1 = p[1]; e2 = p[2]; e3 = p[3];
  }
  #pragma unroll 1
  for (; n < nEnd; n += 256) {
    int nn = n + 256;
    float4 f0 = make_float4(0.f,0.f,0.f,0.f), f1 = f0, f2 = f0, f3 = f0;
    if (nn < nEnd) {
      const float4* p = (const float4*)(emb + (size_t)nn * 16);
      f0 = p[0]; f1 = p[1]; f2 = p[2]; f3 = p[3];
    }
    #pragma unroll
    for (int k = 0; k < 10; ++k) {
      const float4 r0 = *(const float4*)(rxs + k * 16);
      const float4 r1 = *(const float4*)(rxs + k * 16 + 4);
      const float4 r2 = *(const float4*)(rxs + k * 16 + 8);
      const float4 r3 = *(const float4*)(rxs + k * 16 + 12);
      float x0 = fmaf(e0.w, r0.w, fmaf(e0.z, r0.z, fmaf(e0.y, r0.y, e0.x * r0.x)));
      float x1 = fmaf(e1.w, r1.w, fmaf(e1.z, r1.z, fmaf(e1.y, r1.y, e1.x * r1.x)));
      float x2 = fmaf(e2.w, r2.w, fmaf(e2.z, r2.z, fmaf(e2.y, r2.y, e2.x * r2.x)));
      float x3 = fmaf(e3.w, r3.w, fmaf(e3.z, r3.z, fmaf(e3.y, r3.y, e3.x * r3.x)));
      float x = (x0 + x1) + (x2 + x3);
      float mn = fmaxf(m[k], x);
      float al = __builtin_amdgcn_exp2f(-fabsf(x - m[k]));  // v_exp with -|.| modifier
      bool up = x > m[k];
      s[k] = up ? fmaf(s[k], al, 1.0f) : (s[k] + al);
      am[k] = up ? n : am[k];
      m[k] = mn;
    }
    e0 = f0; e1 = f1; e2 = f2; e3 = f3;
  }
  // wave reduce (64 lanes); lower index wins ties
  #pragma unroll
  for (int off = 32; off > 0; off >>= 1) {
    #pragma unroll
    for (int k = 0; k < 10; ++k) {
      float om = __shfl_down(m[k], off);
      float os = __shfl_down(s[k], off);
      int oa = __shfl_down(am[k], off);
      float M2 = fmaxf(m[k], om);
      s[k] = s[k] * __builtin_amdgcn_exp2f(m[k] - M2) + os * __builtin_amdgcn_exp2f(om - M2);
      am[k] = (om > m[k]) ? oa : ((m[k] > om) ? am[k] : (am[k] < oa ? am[k] : oa));
      m[k] = M2;
    }
  }
  int lane = t & 63, wv = t >> 6;
  if (lane == 0) {
    #pragma unroll
    for (int k = 0; k < 10; ++k) { wm[wv][k] = m[k]; wsum[wv][k] = s[k]; wa[wv][k] = am[k]; }
  }
  __syncthreads();
  if (t < 10) {
    int k = t;
    float M = wm[0][k], S = wsum[0][k];
    int AM = wa[0][k];
    #pragma unroll
    for (int w = 1; w < 4; ++w) {
      float m2 = wm[w][k];
      float M2 = fmaxf(M, m2);
      S = S * __builtin_amdgcn_exp2f(M - M2) + wsum[w][k] * __builtin_amdgcn_exp2f(m2 - M2);
      AM = (m2 > M) ? wa[w][k] : ((M > m2) ? AM : (AM < wa[w][k] ? AM : wa[w][k]));
      M = M2;
    }
    int idx = (b * NCHUNK + c) * 10 + k;
    pmg[idx] = M; psg[idx] = S; pag[idx] = AM;
  }
}

// Combine 8 chunk-partials per (b,k); argmax + slate prob (log2 domain).
__global__ __launch_bounds__(256) void score_final(const float* __restrict__ pmg,
    const float* __restrict__ psg, const int* __restrict__ pag,
    const float* __restrict__ rx, const float* __restrict__ emb,
    const int* __restrict__ slate, float* __restrict__ out) {
  int tid = blockIdx.x * 256 + threadIdx.x;
  if (tid >= BATCH * 10) return;
  int b = tid / 10, k = tid % 10;
  int base = b * NCHUNK * 10 + k;
  float M = pmg[base], S = psg[base];
  int AM = pag[base];
  #pragma unroll
  for (int c = 1; c < NCHUNK; ++c) {
    float m2 = pmg[base + c * 10];
    float M2 = fmaxf(M, m2);
    S = S * __builtin_amdgcn_exp2f(M - M2) + psg[base + c * 10] * __builtin_amdgcn_exp2f(m2 - M2);
    int oa = pag[base + c * 10];
    AM = (m2 > M) ? oa : ((M > m2) ? AM : (AM < oa ? AM : oa));
    M = M2;
  }
  int it = slate[b * 10 + k];
  const float* er = emb + (size_t)it * 16;
  const float* rr = rx + b * 160 + k * 16;
  float xs = 0.f;
  #pragma unroll
  for (int e = 0; e < 16; ++e) xs = fmaf(rr[e], er[e], xs);
  out[OUT_RS + b * 10 + k] = (float)AM;
  out[OUT_RR + b * 10 + k] = __builtin_amdgcn_exp2f(fmaf(xs, LOG2E, -M)) / S;
}

extern "C" void kernel_launch(void* const* d_in, const int* in_sizes, int n_in,
                              void* d_out, int out_size, void* d_ws, size_t ws_size,
                              hipStream_t stream) {
  const int* user_repr = (const int*)d_in[0];
  const int* slate = (const int*)d_in[1];
  const float* resp = (const float*)d_in[2];
  const float* eps = (const float*)d_in[3];
  const float* emb = (const float*)d_in[4];
  const float* W_enc = (const float*)d_in[5];
  const float* b_enc = (const float*)d_in[6];
  const float* W_mu = (const float*)d_in[7];
  const float* b_mu = (const float*)d_in[8];
  const float* W_lv = (const float*)d_in[9];
  const float* b_lv = (const float*)d_in[10];
  const float* W_d1 = (const float*)d_in[11];
  const float* b_d1 = (const float*)d_in[12];
  const float* W_d2 = (const float*)d_in[13];
  const float* b_d2 = (const float*)d_in[14];
  float* out = (float*)d_out;
  float* ws = (float*)d_ws;

  float* usum = ws + WS_USUM;
  float* cnt  = ws + WS_CNT;
  float* x    = ws + WS_X;
  float* dz   = ws + WS_DZ;
  float* dh   = ws + WS_DH;
  float* rx   = ws + WS_RX;
  float* part = ws + WS_PART;
  float* spm  = ws + WS_SPM;
  float* sps  = ws + WS_SPS;
  int*   spa  = (int*)(ws + WS_SPA);

  zero_kernel<<<17, 256, 0, stream>>>(usum, 4352);  // usum + cnt
  pool_kernel<<<dim3(256, 8), 256, 0, stream>>>(user_repr, emb, usum, cnt);
  build_x_kernel<<<256, 256, 0, stream>>>(slate, resp, emb, usum, cnt, x, dz);

  // encoder: h partials (folded reduce into mulv_z)
  gemm64<<<dim3(8, 4, 4), 256, 0, stream>>>(x, W_enc, part, 256, 512, 1200, 300);
  mulv_z_kernel<<<256, 128, 0, stream>>>(part, b_enc, W_mu, b_mu, W_lv, b_lv, eps, out, dz);
  // decoder layer 1
  gemm64<<<dim3(8, 4, 4), 256, 0, stream>>>(dz, W_d1, part, 256, 512, 1104, 276);
  reduce_bias<true><<<512, 256, 0, stream>>>(part, b_d1, dh, 131072, 512, 4);
  // decoder layer 2 (N=160, guarded)
  gemm64<<<dim3(3, 4, 8), 256, 0, stream>>>(dh, W_d2, part, 256, 160, 512, 64);
  reduce_bias<true><<<160, 256, 0, stream>>>(part, b_d2, rx, 40960, 160, 8);

  score_part<<<dim3(256, 8), 256, 0, stream>>>(rx, emb, spm, sps, spa);
  score_final<<<10, 256, 0, stream>>>(spm, sps, spa, rx, emb, slate, out);
}